// Round 6
// baseline (3019.038 us; speedup 1.0000x reference)
//
#include <hip/hip_runtime.h>
#include <math.h>

#define SEQ   2048
#define BATCH  128
#define NINP    64
#define NHID   128
#define NOUT    10
#define RPB      4              // batch rows per block
#define NBLK  (BATCH / RPB)

// ---------------------------------------------------------------------------
// K1: xW[s][b][j] = sum_i x[s][b][i]*Wxh[i][j] + bh[j]
// (unchanged — verified correct)
// ---------------------------------------------------------------------------
__global__ __launch_bounds__(256) void proj_kernel(const float* __restrict__ x,
                                                   const float* __restrict__ Wxh,
                                                   const float* __restrict__ bh,
                                                   float* __restrict__ xw) {
    __shared__ float Wlds[NINP * NHID];   // 32 KB
    __shared__ float xs[32 * NINP];       // 8 KB
    const int t = threadIdx.x;
    const size_t r0 = (size_t)blockIdx.x * 32;

#pragma unroll
    for (int i = 0; i < 8; ++i)
        ((float4*)Wlds)[t + 256 * i] = ((const float4*)Wxh)[t + 256 * i];
    const float4* xg = (const float4*)(x + r0 * NINP);
    ((float4*)xs)[t]       = xg[t];
    ((float4*)xs)[t + 256] = xg[t + 256];
    __syncthreads();

    const int tj = t & 31;
    const int tr = t >> 5;
    const int j  = 4 * tj;
    const float4 bhv = *(const float4*)(bh + j);
    float acc[4][4];
#pragma unroll
    for (int r = 0; r < 4; ++r) {
        acc[r][0] = bhv.x; acc[r][1] = bhv.y; acc[r][2] = bhv.z; acc[r][3] = bhv.w;
    }
#pragma unroll 8
    for (int i = 0; i < NINP; ++i) {
        const float4 w4 = *(const float4*)&Wlds[i * NHID + j];
#pragma unroll
        for (int r = 0; r < 4; ++r) {
            const float xv = xs[(4 * tr + r) * NINP + i];
            acc[r][0] = fmaf(xv, w4.x, acc[r][0]);
            acc[r][1] = fmaf(xv, w4.y, acc[r][1]);
            acc[r][2] = fmaf(xv, w4.z, acc[r][2]);
            acc[r][3] = fmaf(xv, w4.w, acc[r][3]);
        }
    }
#pragma unroll
    for (int r = 0; r < 4; ++r) {
        float4 o = { acc[r][0], acc[r][1], acc[r][2], acc[r][3] };
        *(float4*)(xw + (r0 + 4 * tr + r) * NHID + j) = o;
    }
}

// ---------------------------------------------------------------------------
// K2: scan, RPB=4 batch rows per block (4 waves, 256 threads, 32 blocks).
// The per-step sync skeleton (ds_write -> lgkmcnt(0) -> s_barrier -> ds_read
// latency) is paid ONCE per 4 row-steps; phase-A VALU work (shared-weight
// readlane-broadcast matvec) is issue-bound and scales fine.
//   wave w owns k-slice [32w,32w+32) for ALL rows; lane l covers output
//   columns l and 64+l (phase A) and output j0+(l&31) (phase B).
// xw prefetched 3 steps ahead in registers (no LDS staging, no vmcnt drain
// in the loop; raw barriers don't drain vmcnt).
// ---------------------------------------------------------------------------
__global__ __launch_bounds__(256) void scan_kernel(const float* __restrict__ Whh,
                                                   float* __restrict__ hbuf) {
    __shared__ float P[2][RPB][NHID][4];   // 16 KB, double-buffered partials

    const int t  = threadIdx.x;
    const int w  = t >> 6;        // wave 0..3 (k-slice owner)
    const int l  = t & 63;
    const int jj = l & 31;
    const int j0 = 32 * w;
    const int r0 = blockIdx.x * RPB;

    // ---- shared weights: Whh[32w+i][l], Whh[32w+i][64+l] -> 64 pinned VGPRs
    float wx[32], wy[32];
    {
        const float* wp = Whh + (size_t)j0 * NHID + l;
#pragma unroll
        for (int i = 0; i < 32; ++i) {
            wx[i] = wp[(size_t)i * NHID];
            wy[i] = wp[(size_t)i * NHID + 64];
        }
#pragma unroll
        for (int i = 0; i < 32; ++i) {
            asm volatile("" : "+v"(wx[i]));
            asm volatile("" : "+v"(wy[i]));
        }
    }

    // ---- per-row state: h (replicated across lanes of slice) + xw prefetch q
    float vh[RPB], xc[RPB], x1[RPB], x2[RPB];
#pragma unroll
    for (int r = 0; r < RPB; ++r) {
        vh[r] = 0.f;
        const float* p = hbuf + ((size_t)(r0 + r)) * NHID + j0 + jj;
        xc[r] = p[0];                                   // xw[0]
        x1[r] = p[(size_t)1 * BATCH * NHID];            // xw[1]
        x2[r] = p[(size_t)2 * BATCH * NHID];            // xw[2]
    }

    for (int ts = 0; ts < SEQ; ++ts) {
        const int pb = ts & 1;

        // ---- phase A: per-row partials, readlane broadcast (batched by 8)
#pragma unroll
        for (int r = 0; r < RPB; ++r) {
            float ax = 0.f, ay = 0.f;
#pragma unroll
            for (int g = 0; g < 4; ++g) {
                float hr[8];
#pragma unroll
                for (int i = 0; i < 8; ++i)
                    hr[i] = __uint_as_float(__builtin_amdgcn_readlane(
                        __float_as_uint(vh[r]), 8 * g + i));
#pragma unroll
                for (int i = 0; i < 8; ++i) {
                    ax = fmaf(hr[i], wx[8 * g + i], ax);
                    ay = fmaf(hr[i], wy[8 * g + i], ay);
                }
            }
            P[pb][r][l][w]      = ax;   // partial for output column l
            P[pb][r][64 + l][w] = ay;   // partial for output column 64+l
        }

        // one drain + one barrier per 4 row-steps
        asm volatile("s_waitcnt lgkmcnt(0)" ::: "memory");
        __builtin_amdgcn_s_barrier();
        asm volatile("" ::: "memory");

        // ---- phase B: reduce + tanh + store, per row
#pragma unroll
        for (int r = 0; r < RPB; ++r) {
            const float4 p4 = *(const float4*)&P[pb][r][j0 + jj][0];
            const float z  = ((p4.x + p4.y) + (p4.z + p4.w)) + xc[r];
            const float zc = fminf(fmaxf(z, -15.f), 15.f);
            const float e  = __builtin_amdgcn_exp2f(zc * 2.8853900817779268f);
            const float hv = (e - 1.f) * __builtin_amdgcn_rcpf(e + 1.f);
            vh[r] = hv;
            // lanes l and l+32 write same value to same address (legal)
            hbuf[((size_t)ts * BATCH + (r0 + r)) * NHID + j0 + jj] = hv;
            xc[r] = x1[r]; x1[r] = x2[r];   // rotate prefetch queue
        }
        // prefetch xw[ts+3] (clamped; tail loads are dead but in-bounds)
        const int tt = (ts + 3 < SEQ) ? (ts + 3) : (SEQ - 1);
#pragma unroll
        for (int r = 0; r < RPB; ++r)
            x2[r] = hbuf[((size_t)tt * BATCH + (r0 + r)) * NHID + j0 + jj];
    }
}

// ---------------------------------------------------------------------------
// K3: logits = h_last @ Why + by
// ---------------------------------------------------------------------------
__global__ __launch_bounds__(256) void head_kernel(const float* __restrict__ hlast,
                                                   const float* __restrict__ Why,
                                                   const float* __restrict__ by,
                                                   float* __restrict__ out) {
    const int idx = blockIdx.x * 256 + threadIdx.x;
    if (idx >= BATCH * NOUT) return;
    const int b = idx / NOUT;
    const int o = idx % NOUT;
    const float* h = hlast + (size_t)b * NHID;
    float acc = by[o];
#pragma unroll 8
    for (int k = 0; k < NHID; ++k)
        acc = fmaf(h[k], Why[(size_t)k * NOUT + o], acc);
    out[idx] = acc;
}

// ---------------------------------------------------------------------------
extern "C" void kernel_launch(void* const* d_in, const int* in_sizes, int n_in,
                              void* d_out, int out_size, void* d_ws, size_t ws_size,
                              hipStream_t stream) {
    const float* x   = (const float*)d_in[0];
    const float* Wxh = (const float*)d_in[1];
    const float* Whh = (const float*)d_in[2];
    const float* Why = (const float*)d_in[3];
    const float* bh  = (const float*)d_in[4];
    const float* by  = (const float*)d_in[5];
    float* out  = (float*)d_out;
    float* hreg = out + BATCH * NOUT;   // h region starts after the 1280 logits

    proj_kernel<<<(SEQ * BATCH) / 32, 256, 0, stream>>>(x, Wxh, bh, hreg);
    scan_kernel<<<NBLK, 256, 0, stream>>>(Whh, hreg);
    head_kernel<<<5, 256, 0, stream>>>(hreg + (size_t)(SEQ - 1) * BATCH * NHID,
                                       Why, by, out);
}

// Round 8
// 2855.778 us; speedup vs baseline: 1.0572x; 1.0572x over previous
//
#include <hip/hip_runtime.h>
#include <math.h>

#define SEQ   2048
#define BATCH  128
#define NINP    64
#define NHID   128
#define NOUT    10
#define RPB      4              // batch rows per block
#define NBLK  (BATCH / RPB)

// ---------------------------------------------------------------------------
// K1: xW[s][b][j] = sum_i x[s][b][i]*Wxh[i][j] + bh[j]
// (unchanged — verified correct)
// ---------------------------------------------------------------------------
__global__ __launch_bounds__(256) void proj_kernel(const float* __restrict__ x,
                                                   const float* __restrict__ Wxh,
                                                   const float* __restrict__ bh,
                                                   float* __restrict__ xw) {
    __shared__ float Wlds[NINP * NHID];   // 32 KB
    __shared__ float xs[32 * NINP];       // 8 KB
    const int t = threadIdx.x;
    const size_t r0 = (size_t)blockIdx.x * 32;

#pragma unroll
    for (int i = 0; i < 8; ++i)
        ((float4*)Wlds)[t + 256 * i] = ((const float4*)Wxh)[t + 256 * i];
    const float4* xg = (const float4*)(x + r0 * NINP);
    ((float4*)xs)[t]       = xg[t];
    ((float4*)xs)[t + 256] = xg[t + 256];
    __syncthreads();

    const int tj = t & 31;
    const int tr = t >> 5;
    const int j  = 4 * tj;
    const float4 bhv = *(const float4*)(bh + j);
    float acc[4][4];
#pragma unroll
    for (int r = 0; r < 4; ++r) {
        acc[r][0] = bhv.x; acc[r][1] = bhv.y; acc[r][2] = bhv.z; acc[r][3] = bhv.w;
    }
#pragma unroll 8
    for (int i = 0; i < NINP; ++i) {
        const float4 w4 = *(const float4*)&Wlds[i * NHID + j];
#pragma unroll
        for (int r = 0; r < 4; ++r) {
            const float xv = xs[(4 * tr + r) * NINP + i];
            acc[r][0] = fmaf(xv, w4.x, acc[r][0]);
            acc[r][1] = fmaf(xv, w4.y, acc[r][1]);
            acc[r][2] = fmaf(xv, w4.z, acc[r][2]);
            acc[r][3] = fmaf(xv, w4.w, acc[r][3]);
        }
    }
#pragma unroll
    for (int r = 0; r < 4; ++r) {
        float4 o = { acc[r][0], acc[r][1], acc[r][2], acc[r][3] };
        *(float4*)(xw + (r0 + 4 * tr + r) * NHID + j) = o;
    }
}

// ---------------------------------------------------------------------------
// K2: scan, RPB=4 rows per block (4 waves, 32 blocks).
// Same structure as R6, with the two measured bugs fixed:
//  - __launch_bounds__(256, 1): allocator targets 1 wave/EU -> no spill of
//    the 64 pinned weight VGPRs (R6: VGPR=56 proved weights went to scratch).
//  - P layout back to w-major [pb][r][4][NHID] (R5-proven conflict-free):
//    write bank = l%32 (2-way l/l+32, free); read = 32 distinct banks + bcast.
// Skeleton (lgkmcnt drain + barrier + LDS read latency) paid once per RPB
// row-steps; phase A is readlane-broadcast matvec (no LDS, issue-bound).
// ---------------------------------------------------------------------------
__global__ __launch_bounds__(256, 1) void scan_kernel(const float* __restrict__ Whh,
                                                      float* __restrict__ hbuf) {
    __shared__ float P[2][RPB][4][NHID];   // 16 KB, double-buffered partials

    const int t  = threadIdx.x;
    const int w  = t >> 6;        // wave 0..3 (k-slice owner)
    const int l  = t & 63;
    const int jj = l & 31;
    const int j0 = 32 * w;
    const int r0 = blockIdx.x * RPB;

    // ---- shared weights: Whh[32w+i][l], Whh[32w+i][64+l] -> 64 pinned VGPRs
    float wx[32], wy[32];
    {
        const float* wp = Whh + (size_t)j0 * NHID + l;
#pragma unroll
        for (int i = 0; i < 32; ++i) {
            wx[i] = wp[(size_t)i * NHID];
            wy[i] = wp[(size_t)i * NHID + 64];
        }
#pragma unroll
        for (int i = 0; i < 32; ++i) {
            asm volatile("" : "+v"(wx[i]));
            asm volatile("" : "+v"(wy[i]));
        }
    }

    // ---- per-row state: h (replicated across slice lanes) + xw prefetch q
    float vh[RPB], xc[RPB], x1[RPB], x2[RPB];
#pragma unroll
    for (int r = 0; r < RPB; ++r) {
        vh[r] = 0.f;
        const float* p = hbuf + ((size_t)(r0 + r)) * NHID + j0 + jj;
        xc[r] = p[0];                                   // xw[0]
        x1[r] = p[(size_t)1 * BATCH * NHID];            // xw[1]
        x2[r] = p[(size_t)2 * BATCH * NHID];            // xw[2]
    }

    for (int ts = 0; ts < SEQ; ++ts) {
        const int pb = ts & 1;

        // ---- phase A: per-row partials, readlane broadcast (batched by 8)
#pragma unroll
        for (int r = 0; r < RPB; ++r) {
            float ax = 0.f, ay = 0.f;
#pragma unroll
            for (int g = 0; g < 4; ++g) {
                float hr[8];
#pragma unroll
                for (int i = 0; i < 8; ++i)
                    hr[i] = __uint_as_float(__builtin_amdgcn_readlane(
                        __float_as_uint(vh[r]), 8 * g + i));
#pragma unroll
                for (int i = 0; i < 8; ++i) {
                    ax = fmaf(hr[i], wx[8 * g + i], ax);
                    ay = fmaf(hr[i], wy[8 * g + i], ay);
                }
            }
            P[pb][r][w][l]      = ax;   // bank l%32: 2-way (free)
            P[pb][r][w][64 + l] = ay;
        }

        // one drain + one barrier per RPB row-steps
        asm volatile("s_waitcnt lgkmcnt(0)" ::: "memory");
        __builtin_amdgcn_s_barrier();
        __builtin_amdgcn_sched_barrier(0);

        // ---- phase B: reduce + tanh + store, per row
#pragma unroll
        for (int r = 0; r < RPB; ++r) {
            const float p0 = P[pb][r][0][j0 + jj];   // 32 banks + l/l+32 bcast
            const float p1 = P[pb][r][1][j0 + jj];
            const float p2 = P[pb][r][2][j0 + jj];
            const float p3 = P[pb][r][3][j0 + jj];
            const float z  = ((p0 + p1) + (p2 + p3)) + xc[r];
            const float zc = fminf(fmaxf(z, -15.f), 15.f);
            const float e  = __builtin_amdgcn_exp2f(zc * 2.8853900817779268f);
            const float hv = (e - 1.f) * __builtin_amdgcn_rcpf(e + 1.f);
            vh[r] = hv;
            // lanes l and l+32 write same value/address (coalescer merges)
            hbuf[((size_t)ts * BATCH + (r0 + r)) * NHID + j0 + jj] = hv;
            xc[r] = x1[r]; x1[r] = x2[r];   // rotate prefetch queue
        }
        // prefetch xw[ts+3] (clamped; tail loads dead but in-bounds)
        const int tt = (ts + 3 < SEQ) ? (ts + 3) : (SEQ - 1);
#pragma unroll
        for (int r = 0; r < RPB; ++r)
            x2[r] = hbuf[((size_t)tt * BATCH + (r0 + r)) * NHID + j0 + jj];
    }
}

// ---------------------------------------------------------------------------
// K3: logits = h_last @ Why + by
// ---------------------------------------------------------------------------
__global__ __launch_bounds__(256) void head_kernel(const float* __restrict__ hlast,
                                                   const float* __restrict__ Why,
                                                   const float* __restrict__ by,
                                                   float* __restrict__ out) {
    const int idx = blockIdx.x * 256 + threadIdx.x;
    if (idx >= BATCH * NOUT) return;
    const int b = idx / NOUT;
    const int o = idx % NOUT;
    const float* h = hlast + (size_t)b * NHID;
    float acc = by[o];
#pragma unroll 8
    for (int k = 0; k < NHID; ++k)
        acc = fmaf(h[k], Why[(size_t)k * NOUT + o], acc);
    out[idx] = acc;
}

// ---------------------------------------------------------------------------
extern "C" void kernel_launch(void* const* d_in, const int* in_sizes, int n_in,
                              void* d_out, int out_size, void* d_ws, size_t ws_size,
                              hipStream_t stream) {
    const float* x   = (const float*)d_in[0];
    const float* Wxh = (const float*)d_in[1];
    const float* Whh = (const float*)d_in[2];
    const float* Why = (const float*)d_in[3];
    const float* bh  = (const float*)d_in[4];
    const float* by  = (const float*)d_in[5];
    float* out  = (float*)d_out;
    float* hreg = out + BATCH * NOUT;   // h region starts after the 1280 logits

    proj_kernel<<<(SEQ * BATCH) / 32, 256, 0, stream>>>(x, Wxh, bh, hreg);
    scan_kernel<<<NBLK, 256, 0, stream>>>(Whh, hreg);
    head_kernel<<<5, 256, 0, stream>>>(hreg + (size_t)(SEQ - 1) * BATCH * NHID,
                                       Why, by, out);
}